// Round 12
// baseline (1164.639 us; speedup 1.0000x reference)
//
#include <hip/hip_runtime.h>
#include <stdint.h>

// ---------------- types / helpers ----------------
typedef __bf16 bf16x8 __attribute__((ext_vector_type(8)));
typedef __bf16 bf16x4 __attribute__((ext_vector_type(4)));
typedef float  f32x4  __attribute__((ext_vector_type(4)));

#define N_NODES 10000
#define T_ROWS  160000
#define HDIM    512
#define PDIM    256
#define NTILES  2500         // T_ROWS / 64
#define NCTILES 157          // ceil(10000/64) center tiles
#define NBLK_AP  102         // persistent AP blocks
#define NBLK_APA 154         // persistent APA blocks (grid = 256 = 1/CU)

__device__ __forceinline__ f32x4 mfma16(bf16x8 a, bf16x8 b, f32x4 c) {
    return __builtin_amdgcn_mfma_f32_16x16x32_bf16(a, b, c, 0, 0, 0);
}

// ---------------- weight packing into MFMA B-fragment order ----------------
// B logical [K][Nc] row-major f32 -> packed bf16 [nt][kt][lane][8]
// lane l of tile (kt,nt) holds B[kt*32 + 8*(l>>4) + e][nt*16 + (l&15)], e=0..7
__device__ __forceinline__ void pack_one(const float* __restrict__ W,
                                         __bf16* __restrict__ out,
                                         int K, int Nc, int ltid) {
    int lane = ltid & 63;
    int t = ltid >> 6;
    int KT = K >> 5;
    int kt = t % KT, nt = t / KT;
    int col = (nt << 4) + (lane & 15);
    int krow = (kt << 5) + ((lane >> 4) << 3);
    __bf16* dst = out + ((size_t)ltid << 3);
#pragma unroll
    for (int e = 0; e < 8; ++e)
        dst[e] = (__bf16)W[(size_t)(krow + e) * Nc + col];
}

// five weight packs + attn rank-1 collapse (v = W1@W2), one launch
__global__ void pack6_kernel(
    const float* __restrict__ tw,    __bf16* __restrict__ twP,
    const float* __restrict__ WeAP,  __bf16* __restrict__ WeAPp,
    const float* __restrict__ WdAP,  __bf16* __restrict__ WdAPp,
    const float* __restrict__ WeAPA, __bf16* __restrict__ WeAPAp,
    const float* __restrict__ WdAPA, __bf16* __restrict__ WdAPAp,
    const float* __restrict__ W1, const float* __restrict__ W2,
    float* __restrict__ vbuf)
{
    int tid = blockIdx.x * 512 + threadIdx.x;
    if      (tid <  8192) pack_one(tw,    twP,    256, 256, tid);
    else if (tid < 24576) pack_one(WeAP,  WeAPp,  256, 512, tid - 8192);
    else if (tid < 40960) pack_one(WdAP,  WdAPp,  512, 256, tid - 24576);
    else if (tid < 73728) pack_one(WeAPA, WeAPAp, 512, 512, tid - 40960);
    else if (tid < 90112) pack_one(WdAPA, WdAPAp, 512, 256, tid - 73728);
    else if (tid < 90624) {
        int k = tid - 90112;
        float s = 0.f;
        for (int j = 0; j < 512; ++j) s += W1[k * 512 + j] * W2[j];
        vbuf[k] = s;
    }
}

// ---------------- persistent fused metapath MLP + segment-sum ----------------
// Per tile: [issue X(t+1) loads -> regs | GEMM1(t)] -> bar -> [ds_write X(t+1),
// h-write] -> bar -> GEMM2(t) -> bar -> dec -> segred. 3 barriers/tile; the
// next tile's X HBM latency+BW hides under GEMM1/GEMM2 compute. 1 block/CU,
// 256-VGPR budget (launch_bounds 512,2) holds the staged tile in registers.
template<int DIN>
__device__ __forceinline__ void path_persist(
    const float* __restrict__ X,
    const __bf16* __restrict__ WeP, const float* __restrict__ be,
    const __bf16* __restrict__ WdP, const float* __restrict__ bd,
    const int* __restrict__ seg,
    float* __restrict__ inj,
    int t0, int stride,
    __bf16* xbuf, __bf16* hbuf, int* segsA, int* segsB)
{
    constexpr int LDX = DIN + 8;
    constexpr int LDH = HDIM + 8;     // 520
    constexpr int LDP = 260;          // f32 dec stride (64*260*4 == 64*520*2)
    constexpr int KT1 = DIN / 32;
    constexpr int NB  = DIN / 32;     // float4 stage loads per thread (8 / 16)
    const int tid = threadIdx.x;
    const int wave = tid >> 6, lane = tid & 63;
    const int lr = lane & 15, lg = lane >> 4;

    // prologue: stage X(t0) + seg(t0) directly
    {
        const float4* Xv = (const float4*)X + (size_t)t0 * 64 * (DIN / 4);
#pragma unroll
        for (int k = 0; k < NB; ++k) {
            int i = tid + k * 512, r = i / (DIN / 4), c4 = i % (DIN / 4);
            float4 f = Xv[i];
            bf16x4 h;
            h[0] = (__bf16)f.x; h[1] = (__bf16)f.y; h[2] = (__bf16)f.z; h[3] = (__bf16)f.w;
            *(bf16x4*)&xbuf[r * LDX + c4 * 4] = h;
        }
        if (tid < 64) segsA[tid] = seg[t0 * 64 + tid];
    }
    __syncthreads();

    int parity = 0;
    for (int t = t0; t < NTILES; t += stride, parity ^= 1) {
        const int tn = t + stride;
        const bool hasNext = tn < NTILES;
        int* segsCur = parity ? segsB : segsA;
        int* segsNxt = parity ? segsA : segsB;

        // ---- A: issue next-tile X loads into registers (+ next segs) ----
        float4 xh[NB];
        int segv = 0;
        if (hasNext) {
            const float4* Xv = (const float4*)X + (size_t)tn * 64 * (DIN / 4);
#pragma unroll
            for (int k = 0; k < NB; ++k) xh[k] = Xv[tid + k * 512];
            if (tid < 64) segv = seg[tn * 64 + tid];
        }

        // ---- B: GEMM1: acc1 = X@We; wave owns 64-col strip; B ping-pong ----
        f32x4 acc1[4][4] = {};
        {
            const __bf16* w1 = WeP + ((size_t)(wave * 4) * KT1) * 512 + lane * 8;
            bf16x8 bX[4], bY[4], a[4];
#pragma unroll
            for (int ct = 0; ct < 4; ++ct) bX[ct] = *(const bf16x8*)&w1[(size_t)(ct * KT1) * 512];
            for (int kt = 0; kt < KT1; kt += 2) {
#pragma unroll
                for (int ct = 0; ct < 4; ++ct)
                    bY[ct] = *(const bf16x8*)&w1[(size_t)(ct * KT1 + kt + 1) * 512];
                int ko = kt * 32 + lg * 8;
#pragma unroll
                for (int rt = 0; rt < 4; ++rt)
                    a[rt] = *(const bf16x8*)&xbuf[(rt * 16 + lr) * LDX + ko];
                __builtin_amdgcn_s_setprio(1);
#pragma unroll
                for (int ct = 0; ct < 4; ++ct)
#pragma unroll
                    for (int rt = 0; rt < 4; ++rt)
                        acc1[rt][ct] = mfma16(a[rt], bX[ct], acc1[rt][ct]);
                __builtin_amdgcn_s_setprio(0);
                int kn = (kt + 2 < KT1) ? kt + 2 : 0;   // clamped (unused last iter)
#pragma unroll
                for (int ct = 0; ct < 4; ++ct)
                    bX[ct] = *(const bf16x8*)&w1[(size_t)(ct * KT1 + kn) * 512];
                ko = (kt + 1) * 32 + lg * 8;
#pragma unroll
                for (int rt = 0; rt < 4; ++rt)
                    a[rt] = *(const bf16x8*)&xbuf[(rt * 16 + lr) * LDX + ko];
                __builtin_amdgcn_s_setprio(1);
#pragma unroll
                for (int ct = 0; ct < 4; ++ct)
#pragma unroll
                    for (int rt = 0; rt < 4; ++rt)
                        acc1[rt][ct] = mfma16(a[rt], bY[ct], acc1[rt][ct]);
                __builtin_amdgcn_s_setprio(0);
            }
        }
        __syncthreads();   // C: xbuf reads done; prev decs reads done

        // ---- D: write staged X(t+1) -> xbuf; h = relu(acc1+bias) -> hbuf ----
        if (hasNext) {
#pragma unroll
            for (int k = 0; k < NB; ++k) {
                int i = tid + k * 512, r = i / (DIN / 4), c4 = i % (DIN / 4);
                bf16x4 h;
                h[0] = (__bf16)xh[k].x; h[1] = (__bf16)xh[k].y;
                h[2] = (__bf16)xh[k].z; h[3] = (__bf16)xh[k].w;
                *(bf16x4*)&xbuf[r * LDX + c4 * 4] = h;
            }
            if (tid < 64) segsNxt[tid] = segv;
        }
#pragma unroll
        for (int ct = 0; ct < 4; ++ct) {
            int col = wave * 64 + ct * 16 + lr;
            float bias = be[col];
#pragma unroll
            for (int rt = 0; rt < 4; ++rt) {
                int rbase = rt * 16 + lg * 4;
#pragma unroll
                for (int j = 0; j < 4; ++j) {
                    float vl = acc1[rt][ct][j] + bias;
                    hbuf[(rbase + j) * LDH + col] = (__bf16)(vl > 0.f ? vl : 0.f);
                }
            }
        }
        __syncthreads();   // E: hbuf + next xbuf visible

        // ---- F: GEMM2: dec = h@Wd; wave owns 32-col strip; A+B ping-pong ----
        f32x4 acc2[4][2] = {};
        {
            const __bf16* w2 = WdP + ((size_t)(wave * 2) * 16) * 512 + lane * 8;
            bf16x8 bX2[2], bY2[2], aX[4], aY[4];
#pragma unroll
            for (int ct = 0; ct < 2; ++ct) bX2[ct] = *(const bf16x8*)&w2[(size_t)(ct * 16) * 512];
#pragma unroll
            for (int rt = 0; rt < 4; ++rt)
                aX[rt] = *(const bf16x8*)&hbuf[(rt * 16 + lr) * LDH + lg * 8];
            for (int kt = 0; kt < 16; kt += 2) {
#pragma unroll
                for (int ct = 0; ct < 2; ++ct)
                    bY2[ct] = *(const bf16x8*)&w2[(size_t)(ct * 16 + kt + 1) * 512];
                int ko = (kt + 1) * 32 + lg * 8;
#pragma unroll
                for (int rt = 0; rt < 4; ++rt)
                    aY[rt] = *(const bf16x8*)&hbuf[(rt * 16 + lr) * LDH + ko];
                __builtin_amdgcn_s_setprio(1);
#pragma unroll
                for (int ct = 0; ct < 2; ++ct)
#pragma unroll
                    for (int rt = 0; rt < 4; ++rt)
                        acc2[rt][ct] = mfma16(aX[rt], bX2[ct], acc2[rt][ct]);
                __builtin_amdgcn_s_setprio(0);
                int kn = (kt + 2 < 16) ? kt + 2 : 0;
#pragma unroll
                for (int ct = 0; ct < 2; ++ct)
                    bX2[ct] = *(const bf16x8*)&w2[(size_t)(ct * 16 + kn) * 512];
                ko = kn * 32 + lg * 8;
#pragma unroll
                for (int rt = 0; rt < 4; ++rt)
                    aX[rt] = *(const bf16x8*)&hbuf[(rt * 16 + lr) * LDH + ko];
                __builtin_amdgcn_s_setprio(1);
#pragma unroll
                for (int ct = 0; ct < 2; ++ct)
#pragma unroll
                    for (int rt = 0; rt < 4; ++rt)
                        acc2[rt][ct] = mfma16(aY[rt], bY2[ct], acc2[rt][ct]);
                __builtin_amdgcn_s_setprio(0);
            }
        }
        __syncthreads();   // G: all h reads done; hbuf reused as f32 dec tile

        // ---- H: dec(+bias) -> decs (overlay hbuf); sorted-run segred ----
        float* decs = (float*)hbuf;
#pragma unroll
        for (int ct = 0; ct < 2; ++ct) {
            int col = wave * 32 + ct * 16 + lr;
            float bias = bd[col];
#pragma unroll
            for (int rt = 0; rt < 4; ++rt) {
                int rbase = rt * 16 + lg * 4;
#pragma unroll
                for (int j = 0; j < 4; ++j)
                    decs[(rbase + j) * LDP + col] = acc2[rt][ct][j] + bias;
            }
        }
        // no barrier: segred reads exactly the columns this wave wrote
        {
            const int c  = wave * 32 + (lane & 31);
            const int rs = (lane >> 5) * 32;
            float run = decs[rs * LDP + c];
            int cur = segsCur[rs];
            int runstart = rs;
#pragma unroll
            for (int r = rs + 1; r < rs + 32; ++r) {
                int s = segsCur[r];
                float v = decs[r * LDP + c];
                if (s == cur) run += v;
                else {
                    if (runstart != rs) inj[(size_t)cur * PDIM + c] = run;
                    else atomicAdd(&inj[(size_t)cur * PDIM + c], run);
                    cur = s; run = v; runstart = r;
                }
            }
            atomicAdd(&inj[(size_t)cur * PDIM + c], run);
        }
    }
}

// ---------------- center tile (reuses xbuf; LDX=264 == AP stride) ----------------
__device__ __forceinline__ void center_body(
    const float* __restrict__ feat, const __bf16* __restrict__ twP,
    float* __restrict__ center, int tile, __bf16* xs)
{
    constexpr int LDX = 264;
    const int tid = threadIdx.x;
    const int row0 = tile * 64;
    __syncthreads();   // guard: prior readers of xs are done
#pragma unroll 4
    for (int i = tid; i < 64 * 64; i += 512) {
        int r = i / 64, c4 = i % 64;
        int row = row0 + r;
        float4 f = {0.f, 0.f, 0.f, 0.f};
        if (row < N_NODES) f = ((const float4*)feat)[(size_t)row * 64 + c4];
        bf16x4 h;
        h[0] = (__bf16)f.x; h[1] = (__bf16)f.y; h[2] = (__bf16)f.z; h[3] = (__bf16)f.w;
        *(bf16x4*)&xs[r * LDX + c4 * 4] = h;
    }
    __syncthreads();

    const int wave = tid >> 6, lane = tid & 63;
    const int lr = lane & 15, lg = lane >> 4;
    f32x4 acc[4][2] = {};
    const __bf16* w = twP + ((size_t)(wave * 2) * 8) * 512 + lane * 8;
    for (int kt = 0; kt < 8; ++kt) {
        int ko = kt * 32 + lg * 8;
        bf16x8 a[4];
#pragma unroll
        for (int rt = 0; rt < 4; ++rt)
            a[rt] = *(const bf16x8*)&xs[(rt * 16 + lr) * LDX + ko];
#pragma unroll
        for (int ct = 0; ct < 2; ++ct) {
            bf16x8 b = *(const bf16x8*)&w[(size_t)(ct * 8 + kt) * 512];
#pragma unroll
            for (int rt = 0; rt < 4; ++rt)
                acc[rt][ct] = mfma16(a[rt], b, acc[rt][ct]);
        }
    }
#pragma unroll
    for (int ct = 0; ct < 2; ++ct) {
        int col = wave * 32 + ct * 16 + lr;
#pragma unroll
        for (int rt = 0; rt < 4; ++rt) {
            int rbase = rt * 16 + lg * 4;
#pragma unroll
            for (int j = 0; j < 4; ++j) {
                int row = row0 + rbase + j;
                if (row < N_NODES) center[(size_t)row * 256 + col] = acc[rt][ct][j];
            }
        }
    }
}

// persistent grid: 102 AP blocks (+ center tiles) / 154 APA blocks = 256 = 1/CU
__global__ __launch_bounds__(512, 2) void paths_kernel(
    const float* __restrict__ featAP,  const float* __restrict__ featAPA,
    const __bf16* __restrict__ WeAPp,  const float* __restrict__ beAP,
    const __bf16* __restrict__ WdAPp,  const float* __restrict__ bdAP,
    const __bf16* __restrict__ WeAPAp, const float* __restrict__ beAPA,
    const __bf16* __restrict__ WdAPAp, const float* __restrict__ bdAPA,
    const int* __restrict__ segAP, const int* __restrict__ segAPA,
    float* __restrict__ injAP, float* __restrict__ injAPA,
    const float* __restrict__ featA, const __bf16* __restrict__ twP,
    float* __restrict__ center)
{
    __shared__ __bf16 xbuf[64 * (HDIM + 8)];   // 66.5 KB (APA stride; AP uses prefix)
    __shared__ __bf16 hbuf[64 * (HDIM + 8)];   // 66.5 KB
    __shared__ int segsA[64], segsB[64];
    int b = blockIdx.x;
    if (b < NBLK_AP) {
        path_persist<256>(featAP, WeAPp, beAP, WdAPp, bdAP, segAP, injAP,
                          b, NBLK_AP, xbuf, hbuf, segsA, segsB);
        for (int c = b; c < NCTILES; c += NBLK_AP)
            center_body(featA, twP, center, c, xbuf);
    } else {
        path_persist<512>(featAPA, WeAPAp, beAPA, WdAPAp, bdAPA, segAPA, injAPA,
                          b - NBLK_AP, NBLK_APA, xbuf, hbuf, segsA, segsB);
    }
}

// ---------------- both scores in one pass; one wave per row ----------------
__global__ __launch_bounds__(256, 4) void score2_kernel(
    const float* __restrict__ center, const float* __restrict__ injAP,
    const float* __restrict__ injAPA, const float* __restrict__ v,
    float* __restrict__ sacc)
{
    const int w = threadIdx.x >> 6, lane = threadIdx.x & 63;
    float l1 = 0.f, l2 = 0.f;
    for (int row = blockIdx.x * 4 + w; row < N_NODES; row += gridDim.x * 4) {
        float x1 = 0.f, x2 = 0.f;
#pragma unroll
        for (int k = 0; k < 4; ++k) {
            int c = lane + k * 64;
            size_t off = (size_t)row * 256 + c;
            float tc = tanhf(center[off]) * v[c];
            float vi = v[256 + c];
            x1 += tc + tanhf(injAP[off]) * vi;
            x2 += tc + tanhf(injAPA[off]) * vi;
        }
#pragma unroll
        for (int o = 32; o > 0; o >>= 1) {
            x1 += __shfl_xor(x1, o);
            x2 += __shfl_xor(x2, o);
        }
        if (lane == 0) {
            l1 += (x1 > 0.f) ? x1 : 0.1f * x1;
            l2 += (x2 > 0.f) ? x2 : 0.1f * x2;
        }
    }
    if (lane == 0) {
        atomicAdd(&sacc[0], l1);
        atomicAdd(&sacc[1], l2);
    }
}

// ---------------- finalize: softmax wts inline, scale inj, classifier, log_softmax ----------------
__global__ __launch_bounds__(256, 4) void final_kernel(
    const float* __restrict__ center, const float* __restrict__ injAP,
    const float* __restrict__ injAPA, const float* __restrict__ sacc,
    const float* __restrict__ Wcls, const float* __restrict__ bcls,
    float* __restrict__ out0, float* __restrict__ out1, float* __restrict__ out2)
{
    __shared__ float zs[4][256];
    float s1 = sacc[0] * (1.f / N_NODES), s2 = sacc[1] * (1.f / N_NODES);
    float m0 = fmaxf(0.f, fmaxf(s1, s2));
    float e0 = expf(0.f - m0), e1 = expf(s1 - m0), e2 = expf(s2 - m0);
    float inv = 1.f / (e0 + e1 + e2);
    const float w1 = e1 * inv, w2 = e2 * inv;

    const int row0 = blockIdx.x * 4;
    for (int idx = threadIdx.x; idx < 1024; idx += 256) {
        int r = idx >> 8, c = idx & 255;
        size_t off = (size_t)(row0 + r) * 256 + c;
        float a = injAP[off] * w1, b = injAPA[off] * w2;
        out1[off] = a; out2[off] = b;
        zs[r][c] = center[off] + 0.5f * (a + b);
    }
    __syncthreads();
    const int g = threadIdx.x >> 6, j = threadIdx.x & 63;  // one wave per row
    float logit = bcls[j];
    for (int k = 0; k < 256; ++k) logit += zs[g][k] * Wcls[k * 64 + j];
    float m = logit;
#pragma unroll
    for (int o = 32; o > 0; o >>= 1) m = fmaxf(m, __shfl_xor(m, o));
    float e = expf(logit - m);
    float se = e;
#pragma unroll
    for (int o = 32; o > 0; o >>= 1) se += __shfl_xor(se, o);
    out0[(size_t)(row0 + g) * 64 + j] = (logit - m) - logf(se);
}

// ---------------- launch ----------------
extern "C" void kernel_launch(void* const* d_in, const int* in_sizes, int n_in,
                              void* d_out, int out_size, void* d_ws, size_t ws_size,
                              hipStream_t stream)
{
    const float* feat_A   = (const float*)d_in[0];
    const float* feat_AP  = (const float*)d_in[1];
    const float* feat_APA = (const float*)d_in[2];
    const int*   seg_AP   = (const int*)d_in[3];
    const int*   seg_APA  = (const int*)d_in[4];
    const float* type_w   = (const float*)d_in[5];
    const float* We_AP    = (const float*)d_in[6];
    const float* be_AP    = (const float*)d_in[7];
    const float* Wd_AP    = (const float*)d_in[8];
    const float* bd_AP    = (const float*)d_in[9];
    const float* We_APA   = (const float*)d_in[10];
    const float* be_APA   = (const float*)d_in[11];
    const float* Wd_APA   = (const float*)d_in[12];
    const float* bd_APA   = (const float*)d_in[13];
    const float* W_attn1  = (const float*)d_in[14];
    const float* W_attn2  = (const float*)d_in[15];
    const float* W_cls    = (const float*)d_in[16];
    const float* b_cls    = (const float*)d_in[17];

    char* ws = (char*)d_ws;
    size_t o = 0;
    auto alloc = [&](size_t bytes) { char* p = ws + o; o += (bytes + 255) & ~size_t(255); return p; };
    float* center = (float*)alloc((size_t)N_NODES * 256 * 4);
    float* injAP  = (float*)alloc((size_t)N_NODES * 256 * 4);
    float* injAPA = (float*)alloc((size_t)N_NODES * 256 * 4);
    float* vbuf   = (float*)alloc(512 * 4);
    float* sacc   = (float*)alloc(256);
    __bf16* twP    = (__bf16*)alloc(256 * 256 * 2);
    __bf16* WeAPp  = (__bf16*)alloc(256 * 512 * 2);
    __bf16* WdAPp  = (__bf16*)alloc(512 * 256 * 2);
    __bf16* WeAPAp = (__bf16*)alloc(512 * 512 * 2);
    __bf16* WdAPAp = (__bf16*)alloc(512 * 256 * 2);

    hipMemsetAsync(injAP,  0, (size_t)N_NODES * 256 * 4, stream);
    hipMemsetAsync(injAPA, 0, (size_t)N_NODES * 256 * 4, stream);
    hipMemsetAsync(sacc,   0, 256, stream);

    pack6_kernel<<<177, 512, 0, stream>>>(type_w, twP, We_AP, WeAPp, Wd_AP, WdAPp,
                                          We_APA, WeAPAp, Wd_APA, WdAPAp,
                                          W_attn1, W_attn2, vbuf);
    paths_kernel<<<NBLK_AP + NBLK_APA, 512, 0, stream>>>(
        feat_AP, feat_APA, WeAPp, be_AP, WdAPp, bd_AP,
        WeAPAp, be_APA, WdAPAp, bd_APA, seg_AP, seg_APA, injAP, injAPA,
        feat_A, twP, center);
    score2_kernel<<<256, 256, 0, stream>>>(center, injAP, injAPA, vbuf, sacc);

    float* out0 = (float*)d_out;
    float* out1 = out0 + (size_t)N_NODES * 64;
    float* out2 = out1 + (size_t)N_NODES * 256;
    final_kernel<<<N_NODES / 4, 256, 0, stream>>>(center, injAP, injAPA, sacc,
                                                  W_cls, b_cls, out0, out1, out2);
}

// Round 13
// 446.301 us; speedup vs baseline: 2.6095x; 2.6095x over previous
//
#include <hip/hip_runtime.h>
#include <stdint.h>

// ---------------- types / helpers ----------------
typedef __bf16 bf16x8 __attribute__((ext_vector_type(8)));
typedef __bf16 bf16x4 __attribute__((ext_vector_type(4)));
typedef float  f32x4  __attribute__((ext_vector_type(4)));

#define N_NODES 10000
#define T_ROWS  160000
#define HDIM    512
#define PDIM    256
#define BM      128
#define NPT     1250         // T_ROWS / BM tiles per path
#define NCTILES 157          // ceil(10000/64) center tiles (BM=64 geometry)

__device__ __forceinline__ f32x4 mfma16(bf16x8 a, bf16x8 b, f32x4 c) {
    return __builtin_amdgcn_mfma_f32_16x16x32_bf16(a, b, c, 0, 0, 0);
}

// ---------------- weight packing into MFMA B-fragment order ----------------
// B logical [K][Nc] row-major f32 -> packed bf16 [nt][kt][lane][8]
// lane l of tile (kt,nt) holds B[kt*32 + 8*(l>>4) + e][nt*16 + (l&15)], e=0..7
__device__ __forceinline__ void pack_one(const float* __restrict__ W,
                                         __bf16* __restrict__ out,
                                         int K, int Nc, int ltid) {
    int lane = ltid & 63;
    int t = ltid >> 6;
    int KT = K >> 5;
    int kt = t % KT, nt = t / KT;
    int col = (nt << 4) + (lane & 15);
    int krow = (kt << 5) + ((lane >> 4) << 3);
    __bf16* dst = out + ((size_t)ltid << 3);
#pragma unroll
    for (int e = 0; e < 8; ++e)
        dst[e] = (__bf16)W[(size_t)(krow + e) * Nc + col];
}

// five weight packs + attn rank-1 collapse (v = W1@W2), one launch
__global__ void pack6_kernel(
    const float* __restrict__ tw,    __bf16* __restrict__ twP,
    const float* __restrict__ WeAP,  __bf16* __restrict__ WeAPp,
    const float* __restrict__ WdAP,  __bf16* __restrict__ WdAPp,
    const float* __restrict__ WeAPA, __bf16* __restrict__ WeAPAp,
    const float* __restrict__ WdAPA, __bf16* __restrict__ WdAPAp,
    const float* __restrict__ W1, const float* __restrict__ W2,
    float* __restrict__ vbuf)
{
    int tid = blockIdx.x * 512 + threadIdx.x;
    if      (tid <  8192) pack_one(tw,    twP,    256, 256, tid);
    else if (tid < 24576) pack_one(WeAP,  WeAPp,  256, 512, tid - 8192);
    else if (tid < 40960) pack_one(WdAP,  WdAPp,  512, 256, tid - 24576);
    else if (tid < 73728) pack_one(WeAPA, WeAPAp, 512, 512, tid - 40960);
    else if (tid < 90112) pack_one(WdAPA, WdAPAp, 512, 256, tid - 73728);
    else if (tid < 90624) {
        int k = tid - 90112;
        float s = 0.f;
        for (int j = 0; j < 512; ++j) s += W1[k * 512 + j] * W2[j];
        vbuf[k] = s;
    }
}

// ---------------- fused metapath MLP + segment-sum, BM=128, 1 block/CU ----------------
// stage X (inline batched) -> GEMM1 (8 row-tiles: 32 MFMA per 4 B-frags, ILP
// covers L2 latency) -> h(bf16) overwrites X in buf -> GEMM2 -> dec(f32)
// overlay -> sorted-run segred. Single acc[8][4] reused by GEMM2 (AGPR reuse).
template<int DIN>
__device__ __forceinline__ void path_body(
    const float* __restrict__ X,
    const __bf16* __restrict__ WeP, const float* __restrict__ be,
    const __bf16* __restrict__ WdP, const float* __restrict__ bd,
    const int* __restrict__ seg,
    float* __restrict__ inj,
    int tile, __bf16* buf, int* segs)
{
    constexpr int LDX = DIN + 8;
    constexpr int LDH = HDIM + 8;       // 520
    constexpr int LDP = 260;            // f32 dec stride (BM*260*4 == BM*520*2)
    constexpr int KT1 = DIN / 32;
    constexpr int NB4 = BM * (DIN / 4) / 512;   // float4 loads per thread (16/32)
    const int tid = threadIdx.x;
    const int row0 = tile * BM;
    if (tid < BM) segs[tid] = seg[row0 + tid];

    // stage X tile f32 -> bf16 LDS; batches of 8 loads in flight
    {
        const float4* Xv = (const float4*)X + (size_t)row0 * (DIN / 4);
#pragma unroll
        for (int bb = 0; bb < NB4 / 8; ++bb) {
            float4 tmp[8];
#pragma unroll
            for (int k = 0; k < 8; ++k)
                tmp[k] = Xv[tid + (bb * 8 + k) * 512];
#pragma unroll
            for (int k = 0; k < 8; ++k) {
                int i = tid + (bb * 8 + k) * 512;
                int r = i / (DIN / 4), c4 = i % (DIN / 4);
                bf16x4 h;
                h[0] = (__bf16)tmp[k].x; h[1] = (__bf16)tmp[k].y;
                h[2] = (__bf16)tmp[k].z; h[3] = (__bf16)tmp[k].w;
                *(bf16x4*)&buf[r * LDX + c4 * 4] = h;
            }
        }
    }
    __syncthreads();

    const int wave = tid >> 6, lane = tid & 63;
    const int lr = lane & 15, lg = lane >> 4;

    // single accumulator array: GEMM1 uses [8][4]; GEMM2 reuses [8][0..1]
    f32x4 acc[8][4];
#pragma unroll
    for (int rt = 0; rt < 8; ++rt)
#pragma unroll
        for (int ct = 0; ct < 4; ++ct) acc[rt][ct] = (f32x4){0.f, 0.f, 0.f, 0.f};

    // ---- GEMM1: acc = X@We; wave owns 64-col strip x 128 rows; B ping-pong ----
    {
        const __bf16* w1 = WeP + ((size_t)(wave * 4) * KT1) * 512 + lane * 8;
        bf16x8 bX[4], bY[4], a[8];
#pragma unroll
        for (int ct = 0; ct < 4; ++ct) bX[ct] = *(const bf16x8*)&w1[(size_t)(ct * KT1) * 512];
        for (int kt = 0; kt < KT1; kt += 2) {
#pragma unroll
            for (int ct = 0; ct < 4; ++ct)
                bY[ct] = *(const bf16x8*)&w1[(size_t)(ct * KT1 + kt + 1) * 512];
            int ko = kt * 32 + lg * 8;
#pragma unroll
            for (int rt = 0; rt < 8; ++rt)
                a[rt] = *(const bf16x8*)&buf[(rt * 16 + lr) * LDX + ko];
            __builtin_amdgcn_s_setprio(1);
#pragma unroll
            for (int ct = 0; ct < 4; ++ct)
#pragma unroll
                for (int rt = 0; rt < 8; ++rt)
                    acc[rt][ct] = mfma16(a[rt], bX[ct], acc[rt][ct]);
            __builtin_amdgcn_s_setprio(0);
            int kn = (kt + 2 < KT1) ? kt + 2 : 0;   // clamped (unused last iter)
#pragma unroll
            for (int ct = 0; ct < 4; ++ct)
                bX[ct] = *(const bf16x8*)&w1[(size_t)(ct * KT1 + kn) * 512];
            ko = (kt + 1) * 32 + lg * 8;
#pragma unroll
            for (int rt = 0; rt < 8; ++rt)
                a[rt] = *(const bf16x8*)&buf[(rt * 16 + lr) * LDX + ko];
            __builtin_amdgcn_s_setprio(1);
#pragma unroll
            for (int ct = 0; ct < 4; ++ct)
#pragma unroll
                for (int rt = 0; rt < 8; ++rt)
                    acc[rt][ct] = mfma16(a[rt], bY[ct], acc[rt][ct]);
            __builtin_amdgcn_s_setprio(0);
        }
    }
    __syncthreads();   // all X reads done; buf may be overwritten

    // write h = relu(acc + bias) as bf16 into buf (stride LDH)
#pragma unroll
    for (int ct = 0; ct < 4; ++ct) {
        int col = wave * 64 + ct * 16 + lr;
        float bias = be[col];
#pragma unroll
        for (int rt = 0; rt < 8; ++rt) {
            int rbase = rt * 16 + lg * 4;
#pragma unroll
            for (int j = 0; j < 4; ++j) {
                float vl = acc[rt][ct][j] + bias;
                buf[(rbase + j) * LDH + col] = (__bf16)(vl > 0.f ? vl : 0.f);
            }
        }
    }
    __syncthreads();

    // ---- GEMM2: dec = h@Wd; wave owns 32-col strip; reuse acc[*][0..1] ----
#pragma unroll
    for (int rt = 0; rt < 8; ++rt)
#pragma unroll
        for (int ct = 0; ct < 2; ++ct) acc[rt][ct] = (f32x4){0.f, 0.f, 0.f, 0.f};
    {
        const __bf16* w2 = WdP + ((size_t)(wave * 2) * 16) * 512 + lane * 8;
        bf16x8 bX2[2], bY2[2], a[8];
#pragma unroll
        for (int ct = 0; ct < 2; ++ct) bX2[ct] = *(const bf16x8*)&w2[(size_t)(ct * 16) * 512];
        for (int kt = 0; kt < 16; kt += 2) {
#pragma unroll
            for (int ct = 0; ct < 2; ++ct)
                bY2[ct] = *(const bf16x8*)&w2[(size_t)(ct * 16 + kt + 1) * 512];
            int ko = kt * 32 + lg * 8;
#pragma unroll
            for (int rt = 0; rt < 8; ++rt)
                a[rt] = *(const bf16x8*)&buf[(rt * 16 + lr) * LDH + ko];
            __builtin_amdgcn_s_setprio(1);
#pragma unroll
            for (int ct = 0; ct < 2; ++ct)
#pragma unroll
                for (int rt = 0; rt < 8; ++rt)
                    acc[rt][ct] = mfma16(a[rt], bX2[ct], acc[rt][ct]);
            __builtin_amdgcn_s_setprio(0);
            int kn = (kt + 2 < 16) ? kt + 2 : 0;
#pragma unroll
            for (int ct = 0; ct < 2; ++ct)
                bX2[ct] = *(const bf16x8*)&w2[(size_t)(ct * 16 + kn) * 512];
            ko = (kt + 1) * 32 + lg * 8;
#pragma unroll
            for (int rt = 0; rt < 8; ++rt)
                a[rt] = *(const bf16x8*)&buf[(rt * 16 + lr) * LDH + ko];
            __builtin_amdgcn_s_setprio(1);
#pragma unroll
            for (int ct = 0; ct < 2; ++ct)
#pragma unroll
                for (int rt = 0; rt < 8; ++rt)
                    acc[rt][ct] = mfma16(a[rt], bY2[ct], acc[rt][ct]);
            __builtin_amdgcn_s_setprio(0);
        }
    }
    __syncthreads();   // all h reads done; buf reused as f32 dec tile

    // store dec(+bias) to LDS  [BM][LDP] f32
    float* decs = (float*)buf;
#pragma unroll
    for (int ct = 0; ct < 2; ++ct) {
        int col = wave * 32 + ct * 16 + lr;
        float bias = bd[col];
#pragma unroll
        for (int rt = 0; rt < 8; ++rt) {
            int rbase = rt * 16 + lg * 4;
#pragma unroll
            for (int j = 0; j < 4; ++j)
                decs[(rbase + j) * LDP + col] = acc[rt][ct][j] + bias;
        }
    }
    // NO barrier: segred reads exactly the columns this wave wrote.

    // segmented reduction: wave owns 32 cols; 2 lanes/col walk 64-row halves.
    // Interior runs -> plain store (memset provides zeros); boundary -> atomic.
    {
        const int c  = wave * 32 + (lane & 31);
        const int rs = (lane >> 5) * 64;
        float run = decs[rs * LDP + c];
        int cur = segs[rs];
        int runstart = rs;
#pragma unroll 8
        for (int r = rs + 1; r < rs + 64; ++r) {
            int s = segs[r];
            float v = decs[r * LDP + c];
            if (s == cur) run += v;
            else {
                if (runstart != rs) inj[(size_t)cur * PDIM + c] = run;
                else atomicAdd(&inj[(size_t)cur * PDIM + c], run);
                cur = s; run = v; runstart = r;
            }
        }
        atomicAdd(&inj[(size_t)cur * PDIM + c], run);
    }
}

// ---------------- center tile (64 rows, reuses buf prefix) ----------------
__device__ __forceinline__ void center_body(
    const float* __restrict__ feat, const __bf16* __restrict__ twP,
    float* __restrict__ center, int tile, __bf16* xs)
{
    constexpr int LDX = 264;
    const int tid = threadIdx.x;
    const int row0 = tile * 64;
#pragma unroll 4
    for (int i = tid; i < 64 * 64; i += 512) {
        int r = i / 64, c4 = i % 64;
        int row = row0 + r;
        float4 f = {0.f, 0.f, 0.f, 0.f};
        if (row < N_NODES) f = ((const float4*)feat)[(size_t)row * 64 + c4];
        bf16x4 h;
        h[0] = (__bf16)f.x; h[1] = (__bf16)f.y; h[2] = (__bf16)f.z; h[3] = (__bf16)f.w;
        *(bf16x4*)&xs[r * LDX + c4 * 4] = h;
    }
    __syncthreads();

    const int wave = tid >> 6, lane = tid & 63;
    const int lr = lane & 15, lg = lane >> 4;
    f32x4 acc[4][2] = {};
    const __bf16* w = twP + ((size_t)(wave * 2) * 8) * 512 + lane * 8;
    for (int kt = 0; kt < 8; ++kt) {
        int ko = kt * 32 + lg * 8;
        bf16x8 a[4];
#pragma unroll
        for (int rt = 0; rt < 4; ++rt)
            a[rt] = *(const bf16x8*)&xs[(rt * 16 + lr) * LDX + ko];
#pragma unroll
        for (int ct = 0; ct < 2; ++ct) {
            bf16x8 b = *(const bf16x8*)&w[(size_t)(ct * 8 + kt) * 512];
#pragma unroll
            for (int rt = 0; rt < 4; ++rt)
                acc[rt][ct] = mfma16(a[rt], b, acc[rt][ct]);
        }
    }
#pragma unroll
    for (int ct = 0; ct < 2; ++ct) {
        int col = wave * 32 + ct * 16 + lr;
#pragma unroll
        for (int rt = 0; rt < 4; ++rt) {
            int rbase = rt * 16 + lg * 4;
#pragma unroll
            for (int j = 0; j < 4; ++j) {
                int row = row0 + rbase + j;
                if (row < N_NODES) center[(size_t)row * 256 + col] = acc[rt][ct][j];
            }
        }
    }
}

// paths (BM=128, parity split) + center tiles appended
__global__ __launch_bounds__(512, 2) void paths_kernel(
    const float* __restrict__ featAP,  const float* __restrict__ featAPA,
    const __bf16* __restrict__ WeAPp,  const float* __restrict__ beAP,
    const __bf16* __restrict__ WdAPp,  const float* __restrict__ bdAP,
    const __bf16* __restrict__ WeAPAp, const float* __restrict__ beAPA,
    const __bf16* __restrict__ WdAPAp, const float* __restrict__ bdAPA,
    const int* __restrict__ segAP, const int* __restrict__ segAPA,
    float* __restrict__ injAP, float* __restrict__ injAPA,
    const float* __restrict__ featA, const __bf16* __restrict__ twP,
    float* __restrict__ center)
{
    __shared__ __bf16 buf[BM * (HDIM + 8)];   // 133 KB: X / h / dec overlay
    __shared__ int segs[BM];
    int bid = blockIdx.x;
    if (bid >= 2 * NPT) {
        center_body(featA, twP, center, bid - 2 * NPT, buf);
        return;
    }
    int tile = bid >> 1;
    if (bid & 1)
        path_body<512>(featAPA, WeAPAp, beAPA, WdAPAp, bdAPA, segAPA, injAPA,
                       tile, buf, segs);
    else
        path_body<256>(featAP, WeAPp, beAP, WdAPp, bdAP, segAP, injAP,
                       tile, buf, segs);
}

// ---------------- both scores in one pass; one wave per row ----------------
__global__ __launch_bounds__(256, 4) void score2_kernel(
    const float* __restrict__ center, const float* __restrict__ injAP,
    const float* __restrict__ injAPA, const float* __restrict__ v,
    float* __restrict__ sacc)
{
    const int w = threadIdx.x >> 6, lane = threadIdx.x & 63;
    float l1 = 0.f, l2 = 0.f;
    for (int row = blockIdx.x * 4 + w; row < N_NODES; row += gridDim.x * 4) {
        float x1 = 0.f, x2 = 0.f;
#pragma unroll
        for (int k = 0; k < 4; ++k) {
            int c = lane + k * 64;
            size_t off = (size_t)row * 256 + c;
            float tc = tanhf(center[off]) * v[c];
            float vi = v[256 + c];
            x1 += tc + tanhf(injAP[off]) * vi;
            x2 += tc + tanhf(injAPA[off]) * vi;
        }
#pragma unroll
        for (int o = 32; o > 0; o >>= 1) {
            x1 += __shfl_xor(x1, o);
            x2 += __shfl_xor(x2, o);
        }
        if (lane == 0) {
            l1 += (x1 > 0.f) ? x1 : 0.1f * x1;
            l2 += (x2 > 0.f) ? x2 : 0.1f * x2;
        }
    }
    if (lane == 0) {
        atomicAdd(&sacc[0], l1);
        atomicAdd(&sacc[1], l2);
    }
}

// ---------------- finalize: softmax wts inline, scale inj, classifier, log_softmax ----------------
__global__ __launch_bounds__(256, 4) void final_kernel(
    const float* __restrict__ center, const float* __restrict__ injAP,
    const float* __restrict__ injAPA, const float* __restrict__ sacc,
    const float* __restrict__ Wcls, const float* __restrict__ bcls,
    float* __restrict__ out0, float* __restrict__ out1, float* __restrict__ out2)
{
    __shared__ float zs[4][256];
    float s1 = sacc[0] * (1.f / N_NODES), s2 = sacc[1] * (1.f / N_NODES);
    float m0 = fmaxf(0.f, fmaxf(s1, s2));
    float e0 = expf(0.f - m0), e1 = expf(s1 - m0), e2 = expf(s2 - m0);
    float inv = 1.f / (e0 + e1 + e2);
    const float w1 = e1 * inv, w2 = e2 * inv;

    const int row0 = blockIdx.x * 4;
    for (int idx = threadIdx.x; idx < 1024; idx += 256) {
        int r = idx >> 8, c = idx & 255;
        size_t off = (size_t)(row0 + r) * 256 + c;
        float a = injAP[off] * w1, b = injAPA[off] * w2;
        out1[off] = a; out2[off] = b;
        zs[r][c] = center[off] + 0.5f * (a + b);
    }
    __syncthreads();
    const int g = threadIdx.x >> 6, j = threadIdx.x & 63;  // one wave per row
    float logit = bcls[j];
    for (int k = 0; k < 256; ++k) logit += zs[g][k] * Wcls[k * 64 + j];
    float m = logit;
#pragma unroll
    for (int o = 32; o > 0; o >>= 1) m = fmaxf(m, __shfl_xor(m, o));
    float e = expf(logit - m);
    float se = e;
#pragma unroll
    for (int o = 32; o > 0; o >>= 1) se += __shfl_xor(se, o);
    out0[(size_t)(row0 + g) * 64 + j] = (logit - m) - logf(se);
}

// ---------------- launch ----------------
extern "C" void kernel_launch(void* const* d_in, const int* in_sizes, int n_in,
                              void* d_out, int out_size, void* d_ws, size_t ws_size,
                              hipStream_t stream)
{
    const float* feat_A   = (const float*)d_in[0];
    const float* feat_AP  = (const float*)d_in[1];
    const float* feat_APA = (const float*)d_in[2];
    const int*   seg_AP   = (const int*)d_in[3];
    const int*   seg_APA  = (const int*)d_in[4];
    const float* type_w   = (const float*)d_in[5];
    const float* We_AP    = (const float*)d_in[6];
    const float* be_AP    = (const float*)d_in[7];
    const float* Wd_AP    = (const float*)d_in[8];
    const float* bd_AP    = (const float*)d_in[9];
    const float* We_APA   = (const float*)d_in[10];
    const float* be_APA   = (const float*)d_in[11];
    const float* Wd_APA   = (const float*)d_in[12];
    const float* bd_APA   = (const float*)d_in[13];
    const float* W_attn1  = (const float*)d_in[14];
    const float* W_attn2  = (const float*)d_in[15];
    const float* W_cls    = (const float*)d_in[16];
    const float* b_cls    = (const float*)d_in[17];

    char* ws = (char*)d_ws;
    size_t o = 0;
    auto alloc = [&](size_t bytes) { char* p = ws + o; o += (bytes + 255) & ~size_t(255); return p; };
    float* center = (float*)alloc((size_t)N_NODES * 256 * 4);
    float* injAP  = (float*)alloc((size_t)N_NODES * 256 * 4);
    float* injAPA = (float*)alloc((size_t)N_NODES * 256 * 4);
    float* vbuf   = (float*)alloc(512 * 4);
    float* sacc   = (float*)alloc(256);
    __bf16* twP    = (__bf16*)alloc(256 * 256 * 2);
    __bf16* WeAPp  = (__bf16*)alloc(256 * 512 * 2);
    __bf16* WdAPp  = (__bf16*)alloc(512 * 256 * 2);
    __bf16* WeAPAp = (__bf16*)alloc(512 * 512 * 2);
    __bf16* WdAPAp = (__bf16*)alloc(512 * 256 * 2);

    hipMemsetAsync(injAP,  0, (size_t)N_NODES * 256 * 4, stream);
    hipMemsetAsync(injAPA, 0, (size_t)N_NODES * 256 * 4, stream);
    hipMemsetAsync(sacc,   0, 256, stream);

    pack6_kernel<<<177, 512, 0, stream>>>(type_w, twP, We_AP, WeAPp, Wd_AP, WdAPp,
                                          We_APA, WeAPAp, Wd_APA, WdAPAp,
                                          W_attn1, W_attn2, vbuf);
    paths_kernel<<<2 * NPT + NCTILES, 512, 0, stream>>>(
        feat_AP, feat_APA, WeAPp, be_AP, WdAPp, bd_AP,
        WeAPAp, be_APA, WdAPAp, bd_APA, seg_AP, seg_APA, injAP, injAPA,
        feat_A, twP, center);
    score2_kernel<<<256, 256, 0, stream>>>(center, injAP, injAPA, vbuf, sacc);

    float* out0 = (float*)d_out;
    float* out1 = out0 + (size_t)N_NODES * 64;
    float* out2 = out1 + (size_t)N_NODES * 256;
    final_kernel<<<N_NODES / 4, 256, 0, stream>>>(center, injAP, injAPA, sacc,
                                                  W_cls, b_cls, out0, out1, out2);
}

// Round 14
// 436.327 us; speedup vs baseline: 2.6692x; 1.0229x over previous
//
#include <hip/hip_runtime.h>
#include <stdint.h>

// ---------------- types / helpers ----------------
typedef __bf16 bf16x8 __attribute__((ext_vector_type(8)));
typedef __bf16 bf16x4 __attribute__((ext_vector_type(4)));
typedef float  f32x4  __attribute__((ext_vector_type(4)));

#define N_NODES 10000
#define T_ROWS  160000
#define HDIM    512
#define PDIM    256
#define NCTILES 157          // ceil(10000/64) center tiles, fused into paths grid
#define PACK_BLKS 177        // pack work blocks
#define ZERO_BLKS 256        // inj zero-fill blocks appended to pack kernel

__device__ __forceinline__ f32x4 mfma16(bf16x8 a, bf16x8 b, f32x4 c) {
    return __builtin_amdgcn_mfma_f32_16x16x32_bf16(a, b, c, 0, 0, 0);
}

// ---------------- weight packing into MFMA B-fragment order ----------------
// B logical [K][Nc] row-major f32 -> packed bf16 [nt][kt][lane][8]
// lane l of tile (kt,nt) holds B[kt*32 + 8*(l>>4) + e][nt*16 + (l&15)], e=0..7
__device__ __forceinline__ void pack_one(const float* __restrict__ W,
                                         __bf16* __restrict__ out,
                                         int K, int Nc, int ltid) {
    int lane = ltid & 63;
    int t = ltid >> 6;
    int KT = K >> 5;
    int kt = t % KT, nt = t / KT;
    int col = (nt << 4) + (lane & 15);
    int krow = (kt << 5) + ((lane >> 4) << 3);
    __bf16* dst = out + ((size_t)ltid << 3);
#pragma unroll
    for (int e = 0; e < 8; ++e)
        dst[e] = (__bf16)W[(size_t)(krow + e) * Nc + col];
}

// five weight packs + attn rank-1 collapse (v = W1@W2) + inj/sacc zero-fill
__global__ void prep_kernel(
    const float* __restrict__ tw,    __bf16* __restrict__ twP,
    const float* __restrict__ WeAP,  __bf16* __restrict__ WeAPp,
    const float* __restrict__ WdAP,  __bf16* __restrict__ WdAPp,
    const float* __restrict__ WeAPA, __bf16* __restrict__ WeAPAp,
    const float* __restrict__ WdAPA, __bf16* __restrict__ WdAPAp,
    const float* __restrict__ W1, const float* __restrict__ W2,
    float* __restrict__ vbuf,
    float* __restrict__ injAP /* injAPA contiguous after */,
    float* __restrict__ sacc)
{
    if (blockIdx.x >= PACK_BLKS) {
        // zero-fill injAP+injAPA (contiguous 2*N_NODES*256 floats) via float4
        int ztid = (blockIdx.x - PACK_BLKS) * 512 + threadIdx.x;
        f32x4 z = {0.f, 0.f, 0.f, 0.f};
        f32x4* dst = (f32x4*)injAP;
        for (int i = ztid; i < 2 * N_NODES * 64; i += ZERO_BLKS * 512)
            dst[i] = z;
        if (blockIdx.x == PACK_BLKS && threadIdx.x < 2) sacc[threadIdx.x] = 0.f;
        return;
    }
    int tid = blockIdx.x * 512 + threadIdx.x;
    if      (tid <  8192) pack_one(tw,    twP,    256, 256, tid);
    else if (tid < 24576) pack_one(WeAP,  WeAPp,  256, 512, tid - 8192);
    else if (tid < 40960) pack_one(WdAP,  WdAPp,  512, 256, tid - 24576);
    else if (tid < 73728) pack_one(WeAPA, WeAPAp, 512, 512, tid - 40960);
    else if (tid < 90112) pack_one(WdAPA, WdAPAp, 512, 256, tid - 73728);
    else if (tid < 90624) {
        int k = tid - 90112;
        float s = 0.f;
        for (int j = 0; j < 512; ++j) s += W1[k * 512 + j] * W2[j];
        vbuf[k] = s;
    }
}

// ---------------- fused metapath MLP + segment-sum (device body) ----------------
// BM=64 (R6/R11 schedule). stage X -> GEMM1 (B 1-deep ping-pong) -> h(bf16) ->
// GEMM2 (A+B ping-pong) -> dec(f32) in LDS -> sorted-run segred (no barrier:
// each wave reads only the dec columns it wrote).
template<int DIN>
__device__ __forceinline__ void path_body(
    const float* __restrict__ X,
    const __bf16* __restrict__ WeP, const float* __restrict__ be,
    const __bf16* __restrict__ WdP, const float* __restrict__ bd,
    const int* __restrict__ seg,
    float* __restrict__ inj,
    int tile, __bf16* buf, int* segs)
{
    constexpr int LDX = DIN + 8;
    constexpr int LDH = HDIM + 8;     // 520
    constexpr int LDP = 260;          // f32 dec tile stride (64*260*4 == 64*520*2)
    constexpr int KT1 = DIN / 32;
    const int tid = threadIdx.x;
    const int row0 = tile * 64;
    if (tid < 64) segs[tid] = seg[row0 + tid];

    // stage X tile f32 -> bf16 LDS (stride LDX)
#pragma unroll 4
    for (int i = tid; i < 64 * (DIN / 4); i += 512) {
        int r = i / (DIN / 4), c4 = i % (DIN / 4);
        float4 f = ((const float4*)X)[(size_t)(row0 + r) * (DIN / 4) + c4];
        bf16x4 h;
        h[0] = (__bf16)f.x; h[1] = (__bf16)f.y; h[2] = (__bf16)f.z; h[3] = (__bf16)f.w;
        *(bf16x4*)&buf[r * LDX + c4 * 4] = h;
    }
    __syncthreads();

    const int wave = tid >> 6, lane = tid & 63;
    const int lr = lane & 15, lg = lane >> 4;

    // ---- GEMM1: acc1 = X@We; wave owns 64-col strip; B 1-deep ping-pong ----
    f32x4 acc1[4][4] = {};
    {
        const __bf16* w1 = WeP + ((size_t)(wave * 4) * KT1) * 512 + lane * 8;
        bf16x8 bX[4], bY[4], a[4];
#pragma unroll
        for (int ct = 0; ct < 4; ++ct) bX[ct] = *(const bf16x8*)&w1[(size_t)(ct * KT1) * 512];
        for (int kt = 0; kt < KT1; kt += 2) {
#pragma unroll
            for (int ct = 0; ct < 4; ++ct)
                bY[ct] = *(const bf16x8*)&w1[(size_t)(ct * KT1 + kt + 1) * 512];
            int ko = kt * 32 + lg * 8;
#pragma unroll
            for (int rt = 0; rt < 4; ++rt)
                a[rt] = *(const bf16x8*)&buf[(rt * 16 + lr) * LDX + ko];
            __builtin_amdgcn_s_setprio(1);
#pragma unroll
            for (int ct = 0; ct < 4; ++ct)
#pragma unroll
                for (int rt = 0; rt < 4; ++rt)
                    acc1[rt][ct] = mfma16(a[rt], bX[ct], acc1[rt][ct]);
            __builtin_amdgcn_s_setprio(0);
            int kn = (kt + 2 < KT1) ? kt + 2 : 0;   // clamped (unused on last iter)
#pragma unroll
            for (int ct = 0; ct < 4; ++ct)
                bX[ct] = *(const bf16x8*)&w1[(size_t)(ct * KT1 + kn) * 512];
            ko = (kt + 1) * 32 + lg * 8;
#pragma unroll
            for (int rt = 0; rt < 4; ++rt)
                a[rt] = *(const bf16x8*)&buf[(rt * 16 + lr) * LDX + ko];
            __builtin_amdgcn_s_setprio(1);
#pragma unroll
            for (int ct = 0; ct < 4; ++ct)
#pragma unroll
                for (int rt = 0; rt < 4; ++rt)
                    acc1[rt][ct] = mfma16(a[rt], bY[ct], acc1[rt][ct]);
            __builtin_amdgcn_s_setprio(0);
        }
    }
    __syncthreads();   // all X reads done; buf may be overwritten

    // write h = relu(acc1 + bias) as bf16 into buf (stride LDH)
#pragma unroll
    for (int ct = 0; ct < 4; ++ct) {
        int col = wave * 64 + ct * 16 + lr;
        float bias = be[col];
#pragma unroll
        for (int rt = 0; rt < 4; ++rt) {
            int rbase = rt * 16 + lg * 4;
#pragma unroll
            for (int j = 0; j < 4; ++j) {
                float vl = acc1[rt][ct][j] + bias;
                buf[(rbase + j) * LDH + col] = (__bf16)(vl > 0.f ? vl : 0.f);
            }
        }
    }
    __syncthreads();

    // ---- GEMM2: dec = h@Wd; wave owns 32-col strip; A+B ping-pong ----
    f32x4 acc2[4][2] = {};
    {
        const __bf16* w2 = WdP + ((size_t)(wave * 2) * 16) * 512 + lane * 8;
        bf16x8 bX2[2], bY2[2], aX[4], aY[4];
#pragma unroll
        for (int ct = 0; ct < 2; ++ct) bX2[ct] = *(const bf16x8*)&w2[(size_t)(ct * 16) * 512];
#pragma unroll
        for (int rt = 0; rt < 4; ++rt)
            aX[rt] = *(const bf16x8*)&buf[(rt * 16 + lr) * LDH + lg * 8];
        for (int kt = 0; kt < 16; kt += 2) {
#pragma unroll
            for (int ct = 0; ct < 2; ++ct)
                bY2[ct] = *(const bf16x8*)&w2[(size_t)(ct * 16 + kt + 1) * 512];
            int ko = (kt + 1) * 32 + lg * 8;
#pragma unroll
            for (int rt = 0; rt < 4; ++rt)
                aY[rt] = *(const bf16x8*)&buf[(rt * 16 + lr) * LDH + ko];
            __builtin_amdgcn_s_setprio(1);
#pragma unroll
            for (int ct = 0; ct < 2; ++ct)
#pragma unroll
                for (int rt = 0; rt < 4; ++rt)
                    acc2[rt][ct] = mfma16(aX[rt], bX2[ct], acc2[rt][ct]);
            __builtin_amdgcn_s_setprio(0);
            int kn = (kt + 2 < 16) ? kt + 2 : 0;
#pragma unroll
            for (int ct = 0; ct < 2; ++ct)
                bX2[ct] = *(const bf16x8*)&w2[(size_t)(ct * 16 + kn) * 512];
            ko = kn * 32 + lg * 8;
#pragma unroll
            for (int rt = 0; rt < 4; ++rt)
                aX[rt] = *(const bf16x8*)&buf[(rt * 16 + lr) * LDH + ko];
            __builtin_amdgcn_s_setprio(1);
#pragma unroll
            for (int ct = 0; ct < 2; ++ct)
#pragma unroll
                for (int rt = 0; rt < 4; ++rt)
                    acc2[rt][ct] = mfma16(aY[rt], bY2[ct], acc2[rt][ct]);
            __builtin_amdgcn_s_setprio(0);
        }
    }
    __syncthreads();   // all h reads done; buf reused as f32 dec tile

    // store dec(+bias) to LDS  [64][LDP] f32
    float* decs = (float*)buf;
#pragma unroll
    for (int ct = 0; ct < 2; ++ct) {
        int col = wave * 32 + ct * 16 + lr;
        float bias = bd[col];
#pragma unroll
        for (int rt = 0; rt < 4; ++rt) {
            int rbase = rt * 16 + lg * 4;
#pragma unroll
            for (int j = 0; j < 4; ++j)
                decs[(rbase + j) * LDP + col] = acc2[rt][ct][j] + bias;
        }
    }
    // NO barrier: segred reads exactly the columns this wave wrote.

    // segmented reduction: wave owns 32 cols; 2 lanes/col walk 32-row halves.
    // Interior runs -> plain store (zero-fill provides zeros); boundary -> atomic.
    {
        const int c  = wave * 32 + (lane & 31);
        const int rs = (lane >> 5) * 32;
        float run = decs[rs * LDP + c];
        int cur = segs[rs];
        int runstart = rs;
#pragma unroll
        for (int r = rs + 1; r < rs + 32; ++r) {
            int s = segs[r];
            float v = decs[r * LDP + c];
            if (s == cur) run += v;
            else {
                if (runstart != rs) inj[(size_t)cur * PDIM + c] = run;
                else atomicAdd(&inj[(size_t)cur * PDIM + c], run);
                cur = s; run = v; runstart = r;
            }
        }
        atomicAdd(&inj[(size_t)cur * PDIM + c], run);
    }
}

// ---------------- center tile (device body, reuses paths LDS buf) ----------------
__device__ __forceinline__ void center_body(
    const float* __restrict__ feat, const __bf16* __restrict__ twP,
    float* __restrict__ center, int tile, __bf16* xs)
{
    constexpr int LDX = 264;
    const int tid = threadIdx.x;
    const int row0 = tile * 64;
#pragma unroll 4
    for (int i = tid; i < 64 * 64; i += 512) {
        int r = i / 64, c4 = i % 64;
        int row = row0 + r;
        float4 f = {0.f, 0.f, 0.f, 0.f};
        if (row < N_NODES) f = ((const float4*)feat)[(size_t)row * 64 + c4];
        bf16x4 h;
        h[0] = (__bf16)f.x; h[1] = (__bf16)f.y; h[2] = (__bf16)f.z; h[3] = (__bf16)f.w;
        *(bf16x4*)&xs[r * LDX + c4 * 4] = h;
    }
    __syncthreads();

    const int wave = tid >> 6, lane = tid & 63;
    const int lr = lane & 15, lg = lane >> 4;
    f32x4 acc[4][2] = {};
    const __bf16* w = twP + ((size_t)(wave * 2) * 8) * 512 + lane * 8;
    for (int kt = 0; kt < 8; ++kt) {
        int ko = kt * 32 + lg * 8;
        bf16x8 a[4];
#pragma unroll
        for (int rt = 0; rt < 4; ++rt)
            a[rt] = *(const bf16x8*)&xs[(rt * 16 + lr) * LDX + ko];
#pragma unroll
        for (int ct = 0; ct < 2; ++ct) {
            bf16x8 b = *(const bf16x8*)&w[(size_t)(ct * 8 + kt) * 512];
#pragma unroll
            for (int rt = 0; rt < 4; ++rt)
                acc[rt][ct] = mfma16(a[rt], b, acc[rt][ct]);
        }
    }
#pragma unroll
    for (int ct = 0; ct < 2; ++ct) {
        int col = wave * 32 + ct * 16 + lr;
#pragma unroll
        for (int rt = 0; rt < 4; ++rt) {
            int rbase = rt * 16 + lg * 4;
#pragma unroll
            for (int j = 0; j < 4; ++j) {
                int row = row0 + rbase + j;
                if (row < N_NODES) center[(size_t)row * 256 + col] = acc[rt][ct][j];
            }
        }
    }
}

// paths + center in one launch (parity split -> phase diversity on each CU)
__global__ __launch_bounds__(512, 4) void paths_kernel(
    const float* __restrict__ featAP,  const float* __restrict__ featAPA,
    const __bf16* __restrict__ WeAPp,  const float* __restrict__ beAP,
    const __bf16* __restrict__ WdAPp,  const float* __restrict__ bdAP,
    const __bf16* __restrict__ WeAPAp, const float* __restrict__ beAPA,
    const __bf16* __restrict__ WdAPAp, const float* __restrict__ bdAPA,
    const int* __restrict__ segAP, const int* __restrict__ segAPA,
    float* __restrict__ injAP, float* __restrict__ injAPA,
    const float* __restrict__ featA, const __bf16* __restrict__ twP,
    float* __restrict__ center)
{
    __shared__ __bf16 buf[64 * (HDIM + 8)];
    __shared__ int segs[64];
    int bid = blockIdx.x;
    if (bid < NCTILES) {
        center_body(featA, twP, center, bid, buf);
        return;
    }
    int p = bid - NCTILES;
    int tile = p >> 1;
    if (p & 1)
        path_body<512>(featAPA, WeAPAp, beAPA, WdAPAp, bdAPA, segAPA, injAPA,
                       tile, buf, segs);
    else
        path_body<256>(featAP, WeAPp, beAP, WdAPp, bdAP, segAP, injAP,
                       tile, buf, segs);
}

// ---------------- both scores in one pass; one wave per row ----------------
__global__ __launch_bounds__(256, 4) void score2_kernel(
    const float* __restrict__ center, const float* __restrict__ injAP,
    const float* __restrict__ injAPA, const float* __restrict__ v,
    float* __restrict__ sacc)
{
    const int w = threadIdx.x >> 6, lane = threadIdx.x & 63;
    float l1 = 0.f, l2 = 0.f;
    for (int row = blockIdx.x * 4 + w; row < N_NODES; row += gridDim.x * 4) {
        float x1 = 0.f, x2 = 0.f;
#pragma unroll
        for (int k = 0; k < 4; ++k) {
            int c = lane + k * 64;
            size_t off = (size_t)row * 256 + c;
            float tc = tanhf(center[off]) * v[c];
            float vi = v[256 + c];
            x1 += tc + tanhf(injAP[off]) * vi;
            x2 += tc + tanhf(injAPA[off]) * vi;
        }
#pragma unroll
        for (int o = 32; o > 0; o >>= 1) {
            x1 += __shfl_xor(x1, o);
            x2 += __shfl_xor(x2, o);
        }
        if (lane == 0) {
            l1 += (x1 > 0.f) ? x1 : 0.1f * x1;
            l2 += (x2 > 0.f) ? x2 : 0.1f * x2;
        }
    }
    if (lane == 0) {
        atomicAdd(&sacc[0], l1);
        atomicAdd(&sacc[1], l2);
    }
}

// ---------------- finalize: softmax wts inline, scale inj, classifier, log_softmax ----------------
__global__ __launch_bounds__(256, 2) void final_kernel(
    const float* __restrict__ center, const float* __restrict__ injAP,
    const float* __restrict__ injAPA, const float* __restrict__ sacc,
    const float* __restrict__ Wcls, const float* __restrict__ bcls,
    float* __restrict__ out0, float* __restrict__ out1, float* __restrict__ out2)
{
    __shared__ float zs[4][256];
    __shared__ float wls[256 * 64];   // staged Wcls (64 KB): coalesced once,
                                      // then conflict-free LDS reads in k-loop
    for (int i = threadIdx.x; i < 256 * 16; i += 256)
        ((f32x4*)wls)[i] = ((const f32x4*)Wcls)[i];

    float s1 = sacc[0] * (1.f / N_NODES), s2 = sacc[1] * (1.f / N_NODES);
    float m0 = fmaxf(0.f, fmaxf(s1, s2));
    float e0 = expf(0.f - m0), e1 = expf(s1 - m0), e2 = expf(s2 - m0);
    float inv = 1.f / (e0 + e1 + e2);
    const float w1 = e1 * inv, w2 = e2 * inv;

    const int row0 = blockIdx.x * 4;
    for (int idx = threadIdx.x; idx < 1024; idx += 256) {
        int r = idx >> 8, c = idx & 255;
        size_t off = (size_t)(row0 + r) * 256 + c;
        float a = injAP[off] * w1, b = injAPA[off] * w2;
        out1[off] = a; out2[off] = b;
        zs[r][c] = center[off] + 0.5f * (a + b);
    }
    __syncthreads();
    const int g = threadIdx.x >> 6, j = threadIdx.x & 63;  // one wave per row
    float logit = bcls[j];
#pragma unroll 4
    for (int k = 0; k < 256; ++k) logit += zs[g][k] * wls[k * 64 + j];
    float m = logit;
#pragma unroll
    for (int o = 32; o > 0; o >>= 1) m = fmaxf(m, __shfl_xor(m, o));
    float e = expf(logit - m);
    float se = e;
#pragma unroll
    for (int o = 32; o > 0; o >>= 1) se += __shfl_xor(se, o);
    out0[(size_t)(row0 + g) * 64 + j] = (logit - m) - logf(se);
}

// ---------------- launch ----------------
extern "C" void kernel_launch(void* const* d_in, const int* in_sizes, int n_in,
                              void* d_out, int out_size, void* d_ws, size_t ws_size,
                              hipStream_t stream)
{
    const float* feat_A   = (const float*)d_in[0];
    const float* feat_AP  = (const float*)d_in[1];
    const float* feat_APA = (const float*)d_in[2];
    const int*   seg_AP   = (const int*)d_in[3];
    const int*   seg_APA  = (const int*)d_in[4];
    const float* type_w   = (const float*)d_in[5];
    const float* We_AP    = (const float*)d_in[6];
    const float* be_AP    = (const float*)d_in[7];
    const float* Wd_AP    = (const float*)d_in[8];
    const float* bd_AP    = (const float*)d_in[9];
    const float* We_APA   = (const float*)d_in[10];
    const float* be_APA   = (const float*)d_in[11];
    const float* Wd_APA   = (const float*)d_in[12];
    const float* bd_APA   = (const float*)d_in[13];
    const float* W_attn1  = (const float*)d_in[14];
    const float* W_attn2  = (const float*)d_in[15];
    const float* W_cls    = (const float*)d_in[16];
    const float* b_cls    = (const float*)d_in[17];

    char* ws = (char*)d_ws;
    size_t o = 0;
    auto alloc = [&](size_t bytes) { char* p = ws + o; o += (bytes + 255) & ~size_t(255); return p; };
    float* center = (float*)alloc((size_t)N_NODES * 256 * 4);
    float* injAP  = (float*)alloc((size_t)N_NODES * 256 * 4);   // contiguous with
    float* injAPA = (float*)alloc((size_t)N_NODES * 256 * 4);   // injAP (zero-fill)
    float* vbuf   = (float*)alloc(512 * 4);
    float* sacc   = (float*)alloc(256);
    __bf16* twP    = (__bf16*)alloc(256 * 256 * 2);
    __bf16* WeAPp  = (__bf16*)alloc(256 * 512 * 2);
    __bf16* WdAPp  = (__bf16*)alloc(512 * 256 * 2);
    __bf16* WeAPAp = (__bf16*)alloc(512 * 512 * 2);
    __bf16* WdAPAp = (__bf16*)alloc(512 * 256 * 2);

    prep_kernel<<<PACK_BLKS + ZERO_BLKS, 512, 0, stream>>>(
        type_w, twP, We_AP, WeAPp, Wd_AP, WdAPp,
        We_APA, WeAPAp, Wd_APA, WdAPAp,
        W_attn1, W_attn2, vbuf, injAP, sacc);
    paths_kernel<<<NCTILES + 2 * (T_ROWS / 64), 512, 0, stream>>>(
        feat_AP, feat_APA, WeAPp, be_AP, WdAPp, bd_AP,
        WeAPAp, be_APA, WdAPAp, bd_APA, seg_AP, seg_APA, injAP, injAPA,
        feat_A, twP, center);
    score2_kernel<<<256, 256, 0, stream>>>(center, injAP, injAPA, vbuf, sacc);

    float* out0 = (float*)d_out;
    float* out1 = out0 + (size_t)N_NODES * 64;
    float* out2 = out1 + (size_t)N_NODES * 256;
    final_kernel<<<N_NODES / 4, 256, 0, stream>>>(center, injAP, injAPA, sacc,
                                                  W_cls, b_cls, out0, out1, out2);
}

// Round 15
// 421.409 us; speedup vs baseline: 2.7637x; 1.0354x over previous
//
#include <hip/hip_runtime.h>
#include <stdint.h>

// ---------------- types / helpers ----------------
typedef __bf16 bf16x8 __attribute__((ext_vector_type(8)));
typedef __bf16 bf16x4 __attribute__((ext_vector_type(4)));
typedef float  f32x4  __attribute__((ext_vector_type(4)));

#define N_NODES 10000
#define T_ROWS  160000
#define HDIM    512
#define PDIM    256
#define NCTILES 157          // ceil(10000/64) center tiles, fused into paths grid
#define PACK_BLKS 177        // pack work blocks
#define ZERO_BLKS 256        // inj zero-fill blocks appended to prep kernel

__device__ __forceinline__ f32x4 mfma16(bf16x8 a, bf16x8 b, f32x4 c) {
    return __builtin_amdgcn_mfma_f32_16x16x32_bf16(a, b, c, 0, 0, 0);
}

// ---------------- weight packing into MFMA B-fragment order ----------------
// B logical [K][Nc] row-major f32 -> packed bf16 [nt][kt][lane][8]
// lane l of tile (kt,nt) holds B[kt*32 + 8*(l>>4) + e][nt*16 + (l&15)], e=0..7
__device__ __forceinline__ void pack_one(const float* __restrict__ W,
                                         __bf16* __restrict__ out,
                                         int K, int Nc, int ltid) {
    int lane = ltid & 63;
    int t = ltid >> 6;
    int KT = K >> 5;
    int kt = t % KT, nt = t / KT;
    int col = (nt << 4) + (lane & 15);
    int krow = (kt << 5) + ((lane >> 4) << 3);
    __bf16* dst = out + ((size_t)ltid << 3);
#pragma unroll
    for (int e = 0; e < 8; ++e)
        dst[e] = (__bf16)W[(size_t)(krow + e) * Nc + col];
}

// five weight packs + attn rank-1 collapse (v = W1@W2) + inj/sacc zero-fill
__global__ void prep_kernel(
    const float* __restrict__ tw,    __bf16* __restrict__ twP,
    const float* __restrict__ WeAP,  __bf16* __restrict__ WeAPp,
    const float* __restrict__ WdAP,  __bf16* __restrict__ WdAPp,
    const float* __restrict__ WeAPA, __bf16* __restrict__ WeAPAp,
    const float* __restrict__ WdAPA, __bf16* __restrict__ WdAPAp,
    const float* __restrict__ W1, const float* __restrict__ W2,
    float* __restrict__ vbuf,
    float* __restrict__ injAP /* injAPA contiguous after */,
    float* __restrict__ sacc)
{
    if (blockIdx.x >= PACK_BLKS) {
        // zero-fill injAP+injAPA (contiguous 2*N_NODES*256 floats) via float4
        int ztid = (blockIdx.x - PACK_BLKS) * 512 + threadIdx.x;
        f32x4 z = {0.f, 0.f, 0.f, 0.f};
        f32x4* dst = (f32x4*)injAP;
        for (int i = ztid; i < 2 * N_NODES * 64; i += ZERO_BLKS * 512)
            dst[i] = z;
        if (blockIdx.x == PACK_BLKS && threadIdx.x < 2) sacc[threadIdx.x] = 0.f;
        return;
    }
    int tid = blockIdx.x * 512 + threadIdx.x;
    if      (tid <  8192) pack_one(tw,    twP,    256, 256, tid);
    else if (tid < 24576) pack_one(WeAP,  WeAPp,  256, 512, tid - 8192);
    else if (tid < 40960) pack_one(WdAP,  WdAPp,  512, 256, tid - 24576);
    else if (tid < 73728) pack_one(WeAPA, WeAPAp, 512, 512, tid - 40960);
    else if (tid < 90112) pack_one(WdAPA, WdAPAp, 512, 256, tid - 73728);
    else if (tid < 90624) {
        int k = tid - 90112;
        float s = 0.f;
        for (int j = 0; j < 512; ++j) s += W1[k * 512 + j] * W2[j];
        vbuf[k] = s;
    }
}

// ---------------- fused metapath MLP + segment-sum (device body) ----------------
// BM=64 (R6/R11 schedule). stage X -> GEMM1 (B 1-deep ping-pong) -> h(bf16) ->
// GEMM2 (A+B ping-pong) -> dec(f32) in LDS -> sorted-run segred (no barrier:
// each wave reads only the dec columns it wrote).
template<int DIN>
__device__ __forceinline__ void path_body(
    const float* __restrict__ X,
    const __bf16* __restrict__ WeP, const float* __restrict__ be,
    const __bf16* __restrict__ WdP, const float* __restrict__ bd,
    const int* __restrict__ seg,
    float* __restrict__ inj,
    int tile, __bf16* buf, int* segs)
{
    constexpr int LDX = DIN + 8;
    constexpr int LDH = HDIM + 8;     // 520
    constexpr int LDP = 260;          // f32 dec tile stride (64*260*4 == 64*520*2)
    constexpr int KT1 = DIN / 32;
    const int tid = threadIdx.x;
    const int row0 = tile * 64;
    if (tid < 64) segs[tid] = seg[row0 + tid];

    // stage X tile f32 -> bf16 LDS (stride LDX)
#pragma unroll 4
    for (int i = tid; i < 64 * (DIN / 4); i += 512) {
        int r = i / (DIN / 4), c4 = i % (DIN / 4);
        float4 f = ((const float4*)X)[(size_t)(row0 + r) * (DIN / 4) + c4];
        bf16x4 h;
        h[0] = (__bf16)f.x; h[1] = (__bf16)f.y; h[2] = (__bf16)f.z; h[3] = (__bf16)f.w;
        *(bf16x4*)&buf[r * LDX + c4 * 4] = h;
    }
    __syncthreads();

    const int wave = tid >> 6, lane = tid & 63;
    const int lr = lane & 15, lg = lane >> 4;

    // ---- GEMM1: acc1 = X@We; wave owns 64-col strip; B 1-deep ping-pong ----
    f32x4 acc1[4][4] = {};
    {
        const __bf16* w1 = WeP + ((size_t)(wave * 4) * KT1) * 512 + lane * 8;
        bf16x8 bX[4], bY[4], a[4];
#pragma unroll
        for (int ct = 0; ct < 4; ++ct) bX[ct] = *(const bf16x8*)&w1[(size_t)(ct * KT1) * 512];
        for (int kt = 0; kt < KT1; kt += 2) {
#pragma unroll
            for (int ct = 0; ct < 4; ++ct)
                bY[ct] = *(const bf16x8*)&w1[(size_t)(ct * KT1 + kt + 1) * 512];
            int ko = kt * 32 + lg * 8;
#pragma unroll
            for (int rt = 0; rt < 4; ++rt)
                a[rt] = *(const bf16x8*)&buf[(rt * 16 + lr) * LDX + ko];
            __builtin_amdgcn_s_setprio(1);
#pragma unroll
            for (int ct = 0; ct < 4; ++ct)
#pragma unroll
                for (int rt = 0; rt < 4; ++rt)
                    acc1[rt][ct] = mfma16(a[rt], bX[ct], acc1[rt][ct]);
            __builtin_amdgcn_s_setprio(0);
            int kn = (kt + 2 < KT1) ? kt + 2 : 0;   // clamped (unused on last iter)
#pragma unroll
            for (int ct = 0; ct < 4; ++ct)
                bX[ct] = *(const bf16x8*)&w1[(size_t)(ct * KT1 + kn) * 512];
            ko = (kt + 1) * 32 + lg * 8;
#pragma unroll
            for (int rt = 0; rt < 4; ++rt)
                a[rt] = *(const bf16x8*)&buf[(rt * 16 + lr) * LDX + ko];
            __builtin_amdgcn_s_setprio(1);
#pragma unroll
            for (int ct = 0; ct < 4; ++ct)
#pragma unroll
                for (int rt = 0; rt < 4; ++rt)
                    acc1[rt][ct] = mfma16(a[rt], bY[ct], acc1[rt][ct]);
            __builtin_amdgcn_s_setprio(0);
        }
    }
    __syncthreads();   // all X reads done; buf may be overwritten

    // write h = relu(acc1 + bias) as bf16 into buf (stride LDH)
#pragma unroll
    for (int ct = 0; ct < 4; ++ct) {
        int col = wave * 64 + ct * 16 + lr;
        float bias = be[col];
#pragma unroll
        for (int rt = 0; rt < 4; ++rt) {
            int rbase = rt * 16 + lg * 4;
#pragma unroll
            for (int j = 0; j < 4; ++j) {
                float vl = acc1[rt][ct][j] + bias;
                buf[(rbase + j) * LDH + col] = (__bf16)(vl > 0.f ? vl : 0.f);
            }
        }
    }
    __syncthreads();

    // ---- GEMM2: dec = h@Wd; wave owns 32-col strip; A+B ping-pong ----
    f32x4 acc2[4][2] = {};
    {
        const __bf16* w2 = WdP + ((size_t)(wave * 2) * 16) * 512 + lane * 8;
        bf16x8 bX2[2], bY2[2], aX[4], aY[4];
#pragma unroll
        for (int ct = 0; ct < 2; ++ct) bX2[ct] = *(const bf16x8*)&w2[(size_t)(ct * 16) * 512];
#pragma unroll
        for (int rt = 0; rt < 4; ++rt)
            aX[rt] = *(const bf16x8*)&buf[(rt * 16 + lr) * LDH + lg * 8];
        for (int kt = 0; kt < 16; kt += 2) {
#pragma unroll
            for (int ct = 0; ct < 2; ++ct)
                bY2[ct] = *(const bf16x8*)&w2[(size_t)(ct * 16 + kt + 1) * 512];
            int ko = (kt + 1) * 32 + lg * 8;
#pragma unroll
            for (int rt = 0; rt < 4; ++rt)
                aY[rt] = *(const bf16x8*)&buf[(rt * 16 + lr) * LDH + ko];
            __builtin_amdgcn_s_setprio(1);
#pragma unroll
            for (int ct = 0; ct < 2; ++ct)
#pragma unroll
                for (int rt = 0; rt < 4; ++rt)
                    acc2[rt][ct] = mfma16(aX[rt], bX2[ct], acc2[rt][ct]);
            __builtin_amdgcn_s_setprio(0);
            int kn = (kt + 2 < 16) ? kt + 2 : 0;
#pragma unroll
            for (int ct = 0; ct < 2; ++ct)
                bX2[ct] = *(const bf16x8*)&w2[(size_t)(ct * 16 + kn) * 512];
            ko = kn * 32 + lg * 8;
#pragma unroll
            for (int rt = 0; rt < 4; ++rt)
                aX[rt] = *(const bf16x8*)&buf[(rt * 16 + lr) * LDH + ko];
            __builtin_amdgcn_s_setprio(1);
#pragma unroll
            for (int ct = 0; ct < 2; ++ct)
#pragma unroll
                for (int rt = 0; rt < 4; ++rt)
                    acc2[rt][ct] = mfma16(aY[rt], bY2[ct], acc2[rt][ct]);
            __builtin_amdgcn_s_setprio(0);
        }
    }
    __syncthreads();   // all h reads done; buf reused as f32 dec tile

    // store dec(+bias) to LDS  [64][LDP] f32
    float* decs = (float*)buf;
#pragma unroll
    for (int ct = 0; ct < 2; ++ct) {
        int col = wave * 32 + ct * 16 + lr;
        float bias = bd[col];
#pragma unroll
        for (int rt = 0; rt < 4; ++rt) {
            int rbase = rt * 16 + lg * 4;
#pragma unroll
            for (int j = 0; j < 4; ++j)
                decs[(rbase + j) * LDP + col] = acc2[rt][ct][j] + bias;
        }
    }
    // NO barrier: segred reads exactly the columns this wave wrote.

    // segmented reduction: wave owns 32 cols; 2 lanes/col walk 32-row halves.
    // Interior runs -> plain store (zero-fill provides zeros); boundary -> atomic.
    {
        const int c  = wave * 32 + (lane & 31);
        const int rs = (lane >> 5) * 32;
        float run = decs[rs * LDP + c];
        int cur = segs[rs];
        int runstart = rs;
#pragma unroll
        for (int r = rs + 1; r < rs + 32; ++r) {
            int s = segs[r];
            float v = decs[r * LDP + c];
            if (s == cur) run += v;
            else {
                if (runstart != rs) inj[(size_t)cur * PDIM + c] = run;
                else atomicAdd(&inj[(size_t)cur * PDIM + c], run);
                cur = s; run = v; runstart = r;
            }
        }
        atomicAdd(&inj[(size_t)cur * PDIM + c], run);
    }
}

// ---------------- center tile (device body, reuses paths LDS buf) ----------------
__device__ __forceinline__ void center_body(
    const float* __restrict__ feat, const __bf16* __restrict__ twP,
    float* __restrict__ center, int tile, __bf16* xs)
{
    constexpr int LDX = 264;
    const int tid = threadIdx.x;
    const int row0 = tile * 64;
#pragma unroll 4
    for (int i = tid; i < 64 * 64; i += 512) {
        int r = i / 64, c4 = i % 64;
        int row = row0 + r;
        float4 f = {0.f, 0.f, 0.f, 0.f};
        if (row < N_NODES) f = ((const float4*)feat)[(size_t)row * 64 + c4];
        bf16x4 h;
        h[0] = (__bf16)f.x; h[1] = (__bf16)f.y; h[2] = (__bf16)f.z; h[3] = (__bf16)f.w;
        *(bf16x4*)&xs[r * LDX + c4 * 4] = h;
    }
    __syncthreads();

    const int wave = tid >> 6, lane = tid & 63;
    const int lr = lane & 15, lg = lane >> 4;
    f32x4 acc[4][2] = {};
    const __bf16* w = twP + ((size_t)(wave * 2) * 8) * 512 + lane * 8;
    for (int kt = 0; kt < 8; ++kt) {
        int ko = kt * 32 + lg * 8;
        bf16x8 a[4];
#pragma unroll
        for (int rt = 0; rt < 4; ++rt)
            a[rt] = *(const bf16x8*)&xs[(rt * 16 + lr) * LDX + ko];
#pragma unroll
        for (int ct = 0; ct < 2; ++ct) {
            bf16x8 b = *(const bf16x8*)&w[(size_t)(ct * 8 + kt) * 512];
#pragma unroll
            for (int rt = 0; rt < 4; ++rt)
                acc[rt][ct] = mfma16(a[rt], b, acc[rt][ct]);
        }
    }
#pragma unroll
    for (int ct = 0; ct < 2; ++ct) {
        int col = wave * 32 + ct * 16 + lr;
#pragma unroll
        for (int rt = 0; rt < 4; ++rt) {
            int rbase = rt * 16 + lg * 4;
#pragma unroll
            for (int j = 0; j < 4; ++j) {
                int row = row0 + rbase + j;
                if (row < N_NODES) center[(size_t)row * 256 + col] = acc[rt][ct][j];
            }
        }
    }
}

// paths + center in one launch (parity split -> phase diversity on each CU)
__global__ __launch_bounds__(512, 4) void paths_kernel(
    const float* __restrict__ featAP,  const float* __restrict__ featAPA,
    const __bf16* __restrict__ WeAPp,  const float* __restrict__ beAP,
    const __bf16* __restrict__ WdAPp,  const float* __restrict__ bdAP,
    const __bf16* __restrict__ WeAPAp, const float* __restrict__ beAPA,
    const __bf16* __restrict__ WdAPAp, const float* __restrict__ bdAPA,
    const int* __restrict__ segAP, const int* __restrict__ segAPA,
    float* __restrict__ injAP, float* __restrict__ injAPA,
    const float* __restrict__ featA, const __bf16* __restrict__ twP,
    float* __restrict__ center)
{
    __shared__ __bf16 buf[64 * (HDIM + 8)];
    __shared__ int segs[64];
    int bid = blockIdx.x;
    if (bid < NCTILES) {
        center_body(featA, twP, center, bid, buf);
        return;
    }
    int p = bid - NCTILES;
    int tile = p >> 1;
    if (p & 1)
        path_body<512>(featAPA, WeAPAp, beAPA, WdAPAp, bdAPA, segAPA, injAPA,
                       tile, buf, segs);
    else
        path_body<256>(featAP, WeAPp, beAP, WdAPp, bdAP, segAP, injAP,
                       tile, buf, segs);
}

// ---------------- both scores in one pass; one wave per row ----------------
__global__ __launch_bounds__(256, 4) void score2_kernel(
    const float* __restrict__ center, const float* __restrict__ injAP,
    const float* __restrict__ injAPA, const float* __restrict__ v,
    float* __restrict__ sacc)
{
    const int w = threadIdx.x >> 6, lane = threadIdx.x & 63;
    float l1 = 0.f, l2 = 0.f;
    for (int row = blockIdx.x * 4 + w; row < N_NODES; row += gridDim.x * 4) {
        float x1 = 0.f, x2 = 0.f;
#pragma unroll
        for (int k = 0; k < 4; ++k) {
            int c = lane + k * 64;
            size_t off = (size_t)row * 256 + c;
            float tc = tanhf(center[off]) * v[c];
            float vi = v[256 + c];
            x1 += tc + tanhf(injAP[off]) * vi;
            x2 += tc + tanhf(injAPA[off]) * vi;
        }
#pragma unroll
        for (int o = 32; o > 0; o >>= 1) {
            x1 += __shfl_xor(x1, o);
            x2 += __shfl_xor(x2, o);
        }
        if (lane == 0) {
            l1 += (x1 > 0.f) ? x1 : 0.1f * x1;
            l2 += (x2 > 0.f) ? x2 : 0.1f * x2;
        }
    }
    if (lane == 0) {
        atomicAdd(&sacc[0], l1);
        atomicAdd(&sacc[1], l2);
    }
}

// ---------------- finalize: softmax wts inline, scale inj, classifier, log_softmax ----------------
__global__ __launch_bounds__(256, 4) void final_kernel(
    const float* __restrict__ center, const float* __restrict__ injAP,
    const float* __restrict__ injAPA, const float* __restrict__ sacc,
    const float* __restrict__ Wcls, const float* __restrict__ bcls,
    float* __restrict__ out0, float* __restrict__ out1, float* __restrict__ out2)
{
    __shared__ float zs[4][256];
    float s1 = sacc[0] * (1.f / N_NODES), s2 = sacc[1] * (1.f / N_NODES);
    float m0 = fmaxf(0.f, fmaxf(s1, s2));
    float e0 = expf(0.f - m0), e1 = expf(s1 - m0), e2 = expf(s2 - m0);
    float inv = 1.f / (e0 + e1 + e2);
    const float w1 = e1 * inv, w2 = e2 * inv;

    const int row0 = blockIdx.x * 4;
    for (int idx = threadIdx.x; idx < 1024; idx += 256) {
        int r = idx >> 8, c = idx & 255;
        size_t off = (size_t)(row0 + r) * 256 + c;
        float a = injAP[off] * w1, b = injAPA[off] * w2;
        out1[off] = a; out2[off] = b;
        zs[r][c] = center[off] + 0.5f * (a + b);
    }
    __syncthreads();
    const int g = threadIdx.x >> 6, j = threadIdx.x & 63;  // one wave per row
    // 4 independent partial sums break the 256-long serial FMA dependency chain
    float p0 = bcls[j], p1 = 0.f, p2 = 0.f, p3 = 0.f;
#pragma unroll 4
    for (int k = 0; k < 256; k += 4) {
        p0 += zs[g][k + 0] * Wcls[(k + 0) * 64 + j];
        p1 += zs[g][k + 1] * Wcls[(k + 1) * 64 + j];
        p2 += zs[g][k + 2] * Wcls[(k + 2) * 64 + j];
        p3 += zs[g][k + 3] * Wcls[(k + 3) * 64 + j];
    }
    float logit = (p0 + p1) + (p2 + p3);
    float m = logit;
#pragma unroll
    for (int o = 32; o > 0; o >>= 1) m = fmaxf(m, __shfl_xor(m, o));
    float e = expf(logit - m);
    float se = e;
#pragma unroll
    for (int o = 32; o > 0; o >>= 1) se += __shfl_xor(se, o);
    out0[(size_t)(row0 + g) * 64 + j] = (logit - m) - logf(se);
}

// ---------------- launch ----------------
extern "C" void kernel_launch(void* const* d_in, const int* in_sizes, int n_in,
                              void* d_out, int out_size, void* d_ws, size_t ws_size,
                              hipStream_t stream)
{
    const float* feat_A   = (const float*)d_in[0];
    const float* feat_AP  = (const float*)d_in[1];
    const float* feat_APA = (const float*)d_in[2];
    const int*   seg_AP   = (const int*)d_in[3];
    const int*   seg_APA  = (const int*)d_in[4];
    const float* type_w   = (const float*)d_in[5];
    const float* We_AP    = (const float*)d_in[6];
    const float* be_AP    = (const float*)d_in[7];
    const float* Wd_AP    = (const float*)d_in[8];
    const float* bd_AP    = (const float*)d_in[9];
    const float* We_APA   = (const float*)d_in[10];
    const float* be_APA   = (const float*)d_in[11];
    const float* Wd_APA   = (const float*)d_in[12];
    const float* bd_APA   = (const float*)d_in[13];
    const float* W_attn1  = (const float*)d_in[14];
    const float* W_attn2  = (const float*)d_in[15];
    const float* W_cls    = (const float*)d_in[16];
    const float* b_cls    = (const float*)d_in[17];

    char* ws = (char*)d_ws;
    size_t o = 0;
    auto alloc = [&](size_t bytes) { char* p = ws + o; o += (bytes + 255) & ~size_t(255); return p; };
    float* center = (float*)alloc((size_t)N_NODES * 256 * 4);
    float* injAP  = (float*)alloc((size_t)N_NODES * 256 * 4);   // contiguous with
    float* injAPA = (float*)alloc((size_t)N_NODES * 256 * 4);   // injAP (zero-fill)
    float* vbuf   = (float*)alloc(512 * 4);
    float* sacc   = (float*)alloc(256);
    __bf16* twP    = (__bf16*)alloc(256 * 256 * 2);
    __bf16* WeAPp  = (__bf16*)alloc(256 * 512 * 2);
    __bf16* WdAPp  = (__bf16*)alloc(512 * 256 * 2);
    __bf16* WeAPAp = (__bf16*)alloc(512 * 512 * 2);
    __bf16* WdAPAp = (__bf16*)alloc(512 * 256 * 2);

    prep_kernel<<<PACK_BLKS + ZERO_BLKS, 512, 0, stream>>>(
        type_w, twP, We_AP, WeAPp, Wd_AP, WdAPp,
        We_APA, WeAPAp, Wd_APA, WdAPAp,
        W_attn1, W_attn2, vbuf, injAP, sacc);
    paths_kernel<<<NCTILES + 2 * (T_ROWS / 64), 512, 0, stream>>>(
        feat_AP, feat_APA, WeAPp, be_AP, WdAPp, bd_AP,
        WeAPAp, be_APA, WdAPAp, bd_APA, seg_AP, seg_APA, injAP, injAPA,
        feat_A, twP, center);
    score2_kernel<<<256, 256, 0, stream>>>(center, injAP, injAPA, vbuf, sacc);

    float* out0 = (float*)d_out;
    float* out1 = out0 + (size_t)N_NODES * 64;
    float* out2 = out1 + (size_t)N_NODES * 256;
    final_kernel<<<N_NODES / 4, 256, 0, stream>>>(center, injAP, injAPA, sacc,
                                                  W_cls, b_cls, out0, out1, out2);
}